// Round 6
// baseline (112.092 us; speedup 1.0000x reference)
//
#include <hip/hip_runtime.h>
#include <math.h>

// StructureLoss: pred [16,2,512,512] f32, mask [16,512,512] f32 -> scalar f32
// loss = mean_b( wbce_b + wiou_b ), weit = 1 + 5*|boxavg31(m) - m|
//
// Single fused kernel: vertical 31-row sliding sums from global (coalesced),
// one LDS round-trip (vsum 64x94 @ stride 95), one barrier, horizontal 31-tap
// slide fused with elementwise math, block partials -> last-block finalize
// (counter mod-1024 trick: no memset needed, poison-safe, graph-replay-safe).
#define B_   16
#define H_   512
#define W_   512
#define HW_  (H_ * W_)
#define KR   15
#define KK_INV (1.0f / 961.0f)
#define MU_  5.0f
#define TH   64
#define TW   64
#define HALO_W 94              // TW + 2*KR
#define VSTRIDE 95             // odd stride -> horizontal LDS reads exactly 2-way (free)
#define NBLK 1024

__global__ __launch_bounds__(256) void structure_loss_fused(
    const float* __restrict__ pred,     // [B,2,H,W]
    const float* __restrict__ mask,     // [B,H,W]
    float* __restrict__ partial,        // [1024][4] in d_ws
    unsigned* __restrict__ counter,     // 1 uint in d_ws (poison-safe, mod trick)
    float* __restrict__ out)            // scalar
{
    __shared__ float vt[TH * VSTRIDE];  // 64 x 95 floats = 24.3 KB
    __shared__ float wsum[4][4];
    __shared__ unsigned isLast;

    const int tid = threadIdx.x;
    const int b   = blockIdx.z;
    const int r0  = blockIdx.y * TH;
    const int c0  = blockIdx.x * TW;
    const int blk = (blockIdx.z * gridDim.y + blockIdx.y) * gridDim.x + blockIdx.x;

    const float* mb = mask + (size_t)b * HW_;
    const float* pb = pred + ((size_t)b * 2 + 1) * HW_;   // channel-1 logits

    // ---- Vertical phase: 376 tasks = 4 row-groups x 94 halo cols ----
    auto vtask = [&](int task) {
        const int rg = task / 94;
        const int cc = task - rg * 94;
        const int gx = c0 - KR + cc;
        const bool xok = ((unsigned)gx < (unsigned)W_);
        const float* colp = mb + gx;
        const int gy0 = r0 + rg * 16 - KR;
        float keep[15];
        float s = 0.0f;
        #pragma unroll
        for (int d = 0; d < 31; ++d) {
            const int gy = gy0 + d;
            float v = 0.0f;
            if (xok && (unsigned)gy < (unsigned)H_) v = colp[gy * W_];
            if (d < 15) keep[d] = v;
            s += v;
        }
        const int o = (rg * 16) * VSTRIDE + cc;
        vt[o] = s;
        #pragma unroll
        for (int i = 1; i < 16; ++i) {
            const int gy = gy0 + 30 + i;
            float v = 0.0f;
            if (xok && (unsigned)gy < (unsigned)H_) v = colp[gy * W_];
            s += v - keep[i - 1];
            vt[o + i * VSTRIDE] = s;
        }
    };
    vtask(tid);
    if (tid < 120) vtask(tid + 256);
    __syncthreads();

    // ---- Horizontal phase + fused elementwise ----
    const int r  = tid >> 2;
    const int ch = tid & 3;
    const int gr = r0 + r;
    const int gcb = c0 + ch * 16;       // 64B-aligned

    float mv[16], pv[16];
    {
        const float4* m4 = (const float4*)(mb + gr * W_ + gcb);
        const float4* p4 = (const float4*)(pb + gr * W_ + gcb);
        #pragma unroll
        for (int q = 0; q < 4; ++q) {
            const float4 a = m4[q];
            const float4 pp = p4[q];
            mv[q*4+0]=a.x;  mv[q*4+1]=a.y;  mv[q*4+2]=a.z;  mv[q*4+3]=a.w;
            pv[q*4+0]=pp.x; pv[q*4+1]=pp.y; pv[q*4+2]=pp.z; pv[q*4+3]=pp.w;
        }
    }

    const int base = r * VSTRIDE + ch * 16;
    float keep[15];
    float s = 0.0f;
    #pragma unroll
    for (int d = 0; d < 31; ++d) {
        const float t = vt[base + d];
        if (d < 15) keep[d] = t;
        s += t;
    }

    float s_w = 0.0f, s_wb = 0.0f, s_in = 0.0f, s_un = 0.0f;
    #pragma unroll
    for (int j = 0; j < 16; ++j) {
        const float avg = s * KK_INV;
        const float m = mv[j];
        const float p = pv[j];

        const float weit = 1.0f + MU_ * fabsf(avg - m);
        // e = exp(-|p|); bce = max(p,0) - p*m + log(1+e); sigmoid = (p>=0?1:e)/(1+e)
        const float e    = __expf(-fabsf(p));
        const float inv  = __builtin_amdgcn_rcpf(1.0f + e);
        const float bce  = fmaxf(p, 0.0f) - p * m + __logf(1.0f + e);
        const float ps   = (p >= 0.0f ? 1.0f : e) * inv;

        s_w  += weit;
        s_wb += weit * bce;
        s_in += ps * m * weit;
        s_un += (ps + m) * weit;

        if (j < 15)
            s += vt[base + 31 + j] - keep[j];
    }

    // ---- block reduction: wave shuffle -> LDS -> one store per component ----
    const int lane = tid & 63;
    const int wid  = tid >> 6;
    float vals[4] = { s_w, s_wb, s_in, s_un };
    #pragma unroll
    for (int q = 0; q < 4; ++q) {
        float v = vals[q];
        #pragma unroll
        for (int off = 32; off > 0; off >>= 1)
            v += __shfl_down(v, off);
        if (lane == 0) wsum[wid][q] = v;
    }
    __syncthreads();
    if (tid < 4) {
        const float tot = wsum[0][tid] + wsum[1][tid] + wsum[2][tid] + wsum[3][tid];
        partial[blk * 4 + tid] = tot;
    }
    __syncthreads();                    // partial stores issued by all writers

    // ---- last-block detection (poison-safe: fires once per launch via mod) ----
    if (tid == 0) {
        __threadfence();                // release partial[] to device scope
        const unsigned old = atomicAdd(counter, 1u);
        isLast = ((old & (NBLK - 1u)) == (NBLK - 1u)) ? 1u : 0u;
    }
    __syncthreads();
    if (isLast == 0u || tid >= 64) return;

    // ---- finalize (one wave): thread t -> batch t>>2, component t&3 ----
    __threadfence();
    const int bb = tid >> 2;
    const int sc = tid & 3;
    float v = 0.0f;
    #pragma unroll 8
    for (int j = 0; j < 64; ++j) {
        const float* src = &partial[((bb << 6) + j) * 4 + sc];
        v += __hip_atomic_load(src, __ATOMIC_RELAXED, __HIP_MEMORY_SCOPE_AGENT);
    }
    const float v1 = __shfl_down(v, 1);
    const float v2 = __shfl_down(v, 2);
    const float v3 = __shfl_down(v, 3);
    float loss = 0.0f;
    if (sc == 0) {
        const float sw = v, swb = v1, inter = v2, uni = v3;
        loss = swb / sw + 1.0f - (inter + 1.0f) / (uni - inter + 1.0f);
    }
    #pragma unroll
    for (int off = 4; off < 64; off <<= 1)
        loss += __shfl_down(loss, off);
    if (tid == 0) out[0] = loss * (1.0f / (float)B_);
}

extern "C" void kernel_launch(void* const* d_in, const int* in_sizes, int n_in,
                              void* d_out, int out_size, void* d_ws, size_t ws_size,
                              hipStream_t stream) {
    const float* pred = (const float*)d_in[0];
    const float* mask = (const float*)d_in[1];
    float* out = (float*)d_out;
    float* partial = (float*)d_ws;                      // 4096 floats, fully overwritten
    unsigned* counter = (unsigned*)((char*)d_ws + NBLK * 4 * sizeof(float));

    dim3 grid(W_ / TW, H_ / TH, B_);    // 8 x 8 x 16 = 1024 blocks
    structure_loss_fused<<<grid, 256, 0, stream>>>(pred, mask, partial, counter, out);
}

// Round 7
// 98.850 us; speedup vs baseline: 1.1340x; 1.1340x over previous
//
#include <hip/hip_runtime.h>
#include <math.h>

// StructureLoss: pred [16,2,512,512] f32, mask [16,512,512] f32 -> scalar f32
// loss = mean_b( wbce_b + wiou_b ), weit = 1 + 5*|boxavg31(m) - m|
//
// R7 = R5 (measured best) + early m/p float4 prefetch to overlap HBM latency
// with the vertical phase. Two kernels — R6 showed single-kernel fusion with
// per-block device-scope fences costs +17 µs (L2 writeback per block).
#define B_   16
#define H_   512
#define W_   512
#define HW_  (H_ * W_)
#define KR   15
#define KK_INV (1.0f / 961.0f)
#define MU_  5.0f
#define TH   64
#define TW   64
#define HALO_W 94              // TW + 2*KR
#define VSTRIDE 95             // odd stride -> horizontal LDS reads 2-way max (free)

__global__ __launch_bounds__(256) void structure_loss_tile(
    const float* __restrict__ pred,     // [B,2,H,W]
    const float* __restrict__ mask,     // [B,H,W]
    float* __restrict__ partial)        // [1024][4]
{
    __shared__ float vt[TH * VSTRIDE];  // 64 x 95 floats = 24.3 KB
    __shared__ float wsum[4][4];

    const int tid = threadIdx.x;
    const int b   = blockIdx.z;
    const int r0  = blockIdx.y * TH;
    const int c0  = blockIdx.x * TW;
    const int blk = (blockIdx.z * gridDim.y + blockIdx.y) * gridDim.x + blockIdx.x;

    const float* mb = mask + (size_t)b * HW_;
    const float* pb = pred + ((size_t)b * 2 + 1) * HW_;   // channel-1 logits

    // ---- Prefetch m/p for the horizontal phase (overlaps vertical phase) ----
    // thread t: row r = t>>2, chunk ch = t&3 -> output cols [ch*16, ch*16+16)
    const int r   = tid >> 2;
    const int ch  = tid & 3;
    const int gr  = r0 + r;
    const int gcb = c0 + ch * 16;       // 64B-aligned
    float mv[16], pv[16];
    {
        const float4* m4 = (const float4*)(mb + gr * W_ + gcb);
        const float4* p4 = (const float4*)(pb + gr * W_ + gcb);
        #pragma unroll
        for (int q = 0; q < 4; ++q) {
            const float4 a = m4[q];
            const float4 pp = p4[q];
            mv[q*4+0]=a.x;  mv[q*4+1]=a.y;  mv[q*4+2]=a.z;  mv[q*4+3]=a.w;
            pv[q*4+0]=pp.x; pv[q*4+1]=pp.y; pv[q*4+2]=pp.z; pv[q*4+3]=pp.w;
        }
    }

    // ---- Vertical phase: 376 tasks = 4 row-groups x 94 halo cols ----
    // task t: rg = t/94, cc = t%94; column gx = c0-15+cc (zero outside image).
    // Produces vt[rg*16+i][cc] = sum_{dr=-15..15} mask[r0+rg*16+i+dr][gx].
    auto vtask = [&](int task) {
        const int rg = task / 94;
        const int cc = task - rg * 94;
        const int gx = c0 - KR + cc;
        const bool xok = ((unsigned)gx < (unsigned)W_);
        const float* colp = mb + gx;
        const int gy0 = r0 + rg * 16 - KR;
        float keep[15];
        float s = 0.0f;
        #pragma unroll
        for (int d = 0; d < 31; ++d) {
            const int gy = gy0 + d;
            float v = 0.0f;
            if (xok && (unsigned)gy < (unsigned)H_) v = colp[gy * W_];
            if (d < 15) keep[d] = v;
            s += v;
        }
        const int o = (rg * 16) * VSTRIDE + cc;
        vt[o] = s;
        #pragma unroll
        for (int i = 1; i < 16; ++i) {
            const int gy = gy0 + 30 + i;
            float v = 0.0f;
            if (xok && (unsigned)gy < (unsigned)H_) v = colp[gy * W_];
            s += v - keep[i - 1];
            vt[o + i * VSTRIDE] = s;
        }
    };
    vtask(tid);
    if (tid < 120) vtask(tid + 256);
    __syncthreads();

    // ---- Horizontal phase + fused elementwise ----
    const int base = r * VSTRIDE + ch * 16;
    float keep[15];
    float s = 0.0f;
    #pragma unroll
    for (int d = 0; d < 31; ++d) {
        const float t = vt[base + d];
        if (d < 15) keep[d] = t;
        s += t;
    }

    float s_w = 0.0f, s_wb = 0.0f, s_in = 0.0f, s_un = 0.0f;
    #pragma unroll
    for (int j = 0; j < 16; ++j) {
        const float avg = s * KK_INV;
        const float m = mv[j];
        const float p = pv[j];

        const float weit = 1.0f + MU_ * fabsf(avg - m);
        // e = exp(-|p|); bce = max(p,0) - p*m + log(1+e); sigmoid = (p>=0?1:e)/(1+e)
        const float e    = __expf(-fabsf(p));
        const float inv  = __builtin_amdgcn_rcpf(1.0f + e);
        const float bce  = fmaxf(p, 0.0f) - p * m + __logf(1.0f + e);
        const float ps   = (p >= 0.0f ? 1.0f : e) * inv;

        s_w  += weit;
        s_wb += weit * bce;
        s_in += ps * m * weit;
        s_un += (ps + m) * weit;

        if (j < 15)
            s += vt[base + 31 + j] - keep[j];
    }

    // ---- block reduction: wave shuffle -> LDS -> one store per component ----
    const int lane = tid & 63;
    const int wid  = tid >> 6;
    float vals[4] = { s_w, s_wb, s_in, s_un };
    #pragma unroll
    for (int q = 0; q < 4; ++q) {
        float v = vals[q];
        #pragma unroll
        for (int off = 32; off > 0; off >>= 1)
            v += __shfl_down(v, off);
        if (lane == 0) wsum[wid][q] = v;
    }
    __syncthreads();
    if (tid < 4) {
        const float tot = wsum[0][tid] + wsum[1][tid] + wsum[2][tid] + wsum[3][tid];
        partial[blk * 4 + tid] = tot;   // unconditional write -> no memset needed
    }
}

__global__ void structure_loss_final(const float* __restrict__ partial,
                                     float* __restrict__ out)
{
    // 64 threads; 4 threads per batch, 16 float4 blocks each, coalesced.
    const int t = threadIdx.x;
    const float4* p4 = (const float4*)partial;   // one float4 per block
    float4 v = make_float4(0.f, 0.f, 0.f, 0.f);
    #pragma unroll
    for (int j = 0; j < 16; ++j) {
        const float4 q = p4[t * 16 + j];
        v.x += q.x; v.y += q.y; v.z += q.z; v.w += q.w;
    }
    #pragma unroll
    for (int off = 2; off > 0; off >>= 1) {
        v.x += __shfl_down(v.x, off);
        v.y += __shfl_down(v.y, off);
        v.z += __shfl_down(v.z, off);
        v.w += __shfl_down(v.w, off);
    }
    float loss = 0.0f;
    if ((t & 3) == 0) {
        const float sw = v.x, swb = v.y, inter = v.z, uni = v.w;
        loss = swb / sw + 1.0f - (inter + 1.0f) / (uni - inter + 1.0f);
    }
    #pragma unroll
    for (int off = 32; off >= 4; off >>= 1)
        loss += __shfl_down(loss, off);
    if (t == 0) out[0] = loss * (1.0f / (float)B_);
}

extern "C" void kernel_launch(void* const* d_in, const int* in_sizes, int n_in,
                              void* d_out, int out_size, void* d_ws, size_t ws_size,
                              hipStream_t stream) {
    const float* pred = (const float*)d_in[0];
    const float* mask = (const float*)d_in[1];
    float* out = (float*)d_out;
    float* partial = (float*)d_ws;      // 1024*4 floats, fully overwritten each call

    dim3 grid(W_ / TW, H_ / TH, B_);    // 8 x 8 x 16 = 1024 blocks
    structure_loss_tile<<<grid, 256, 0, stream>>>(pred, mask, partial);
    structure_loss_final<<<1, 64, 0, stream>>>(partial, out);
}

// Round 8
// 94.873 us; speedup vs baseline: 1.1815x; 1.0419x over previous
//
#include <hip/hip_runtime.h>
#include <math.h>

// StructureLoss: pred [16,2,512,512] f32, mask [16,512,512] f32 -> scalar f32
// loss = mean_b( wbce_b + wiou_b ), weit = 1 + 5*|boxavg31(m) - m|
//
// R8 = exact revert to R5 (measured best, 94.55 µs):
//  - vertical 31-row sliding sums straight from global (coalesced),
//  - ONE LDS round-trip (vsum 64x94 @ stride 95, odd -> 2-way banks = free),
//  - one barrier, horizontal 31-tap slide fused with elementwise math,
//  - m/p float4 loads AFTER the barrier (R7 showed hoisting them costs +4 µs),
//  - two dispatches (R6 showed in-kernel finalize w/ device fences costs +17 µs).
#define B_   16
#define H_   512
#define W_   512
#define HW_  (H_ * W_)
#define KR   15
#define KK_INV (1.0f / 961.0f)
#define MU_  5.0f
#define TH   64
#define TW   64
#define HALO_W 94              // TW + 2*KR
#define VSTRIDE 95             // odd stride -> horizontal LDS reads exactly 2-way (free)

__global__ __launch_bounds__(256) void structure_loss_tile(
    const float* __restrict__ pred,     // [B,2,H,W]
    const float* __restrict__ mask,     // [B,H,W]
    float* __restrict__ partial)        // [1024][4]
{
    __shared__ float vt[TH * VSTRIDE];  // 64 x 95 floats = 24.3 KB
    __shared__ float wsum[4][4];

    const int tid = threadIdx.x;
    const int b   = blockIdx.z;
    const int r0  = blockIdx.y * TH;
    const int c0  = blockIdx.x * TW;
    const int blk = (blockIdx.z * gridDim.y + blockIdx.y) * gridDim.x + blockIdx.x;

    const float* mb = mask + (size_t)b * HW_;
    const float* pb = pred + ((size_t)b * 2 + 1) * HW_;   // channel-1 logits

    // ---- Vertical phase: 376 tasks = 4 row-groups x 94 halo cols ----
    // task t: rg = t/94, cc = t%94; column gx = c0-15+cc (zero outside image).
    // Produces vt[rg*16+i][cc] = sum_{dr=-15..15} mask[r0+rg*16+i+dr][gx].
    // Lane->cc mapping is consecutive -> global reads coalesced per step.
    auto vtask = [&](int task) {
        const int rg = task / 94;
        const int cc = task - rg * 94;
        const int gx = c0 - KR + cc;
        const bool xok = ((unsigned)gx < (unsigned)W_);
        const float* colp = mb + gx;
        const int gy0 = r0 + rg * 16 - KR;
        float keep[15];
        float s = 0.0f;
        #pragma unroll
        for (int d = 0; d < 31; ++d) {
            const int gy = gy0 + d;
            float v = 0.0f;
            if (xok && (unsigned)gy < (unsigned)H_) v = colp[gy * W_];
            if (d < 15) keep[d] = v;
            s += v;
        }
        const int o = (rg * 16) * VSTRIDE + cc;
        vt[o] = s;
        #pragma unroll
        for (int i = 1; i < 16; ++i) {
            const int gy = gy0 + 30 + i;
            float v = 0.0f;
            if (xok && (unsigned)gy < (unsigned)H_) v = colp[gy * W_];
            s += v - keep[i - 1];
            vt[o + i * VSTRIDE] = s;
        }
    };
    vtask(tid);
    if (tid < 120) vtask(tid + 256);
    __syncthreads();

    // ---- Horizontal phase + fused elementwise ----
    // thread t: row r = t>>2, chunk ch = t&3 -> output cols [ch*16, ch*16+16)
    const int r  = tid >> 2;
    const int ch = tid & 3;
    const int gr = r0 + r;
    const int gcb = c0 + ch * 16;       // 64B-aligned

    float mv[16], pv[16];
    {
        const float4* m4 = (const float4*)(mb + gr * W_ + gcb);
        const float4* p4 = (const float4*)(pb + gr * W_ + gcb);
        #pragma unroll
        for (int q = 0; q < 4; ++q) {
            const float4 a = m4[q];
            const float4 pp = p4[q];
            mv[q*4+0]=a.x;  mv[q*4+1]=a.y;  mv[q*4+2]=a.z;  mv[q*4+3]=a.w;
            pv[q*4+0]=pp.x; pv[q*4+1]=pp.y; pv[q*4+2]=pp.z; pv[q*4+3]=pp.w;
        }
    }

    const int base = r * VSTRIDE + ch * 16;
    float keep[15];
    float s = 0.0f;
    #pragma unroll
    for (int d = 0; d < 31; ++d) {
        const float t = vt[base + d];
        if (d < 15) keep[d] = t;
        s += t;
    }

    float s_w = 0.0f, s_wb = 0.0f, s_in = 0.0f, s_un = 0.0f;
    #pragma unroll
    for (int j = 0; j < 16; ++j) {
        const float avg = s * KK_INV;
        const float m = mv[j];
        const float p = pv[j];

        const float weit = 1.0f + MU_ * fabsf(avg - m);
        // e = exp(-|p|); bce = max(p,0) - p*m + log(1+e); sigmoid = (p>=0?1:e)/(1+e)
        const float e    = __expf(-fabsf(p));
        const float inv  = __builtin_amdgcn_rcpf(1.0f + e);
        const float bce  = fmaxf(p, 0.0f) - p * m + __logf(1.0f + e);
        const float ps   = (p >= 0.0f ? 1.0f : e) * inv;

        s_w  += weit;
        s_wb += weit * bce;
        s_in += ps * m * weit;
        s_un += (ps + m) * weit;

        if (j < 15)
            s += vt[base + 31 + j] - keep[j];
    }

    // ---- block reduction: wave shuffle -> LDS -> one store per component ----
    const int lane = tid & 63;
    const int wid  = tid >> 6;
    float vals[4] = { s_w, s_wb, s_in, s_un };
    #pragma unroll
    for (int q = 0; q < 4; ++q) {
        float v = vals[q];
        #pragma unroll
        for (int off = 32; off > 0; off >>= 1)
            v += __shfl_down(v, off);
        if (lane == 0) wsum[wid][q] = v;
    }
    __syncthreads();
    if (tid < 4) {
        const float tot = wsum[0][tid] + wsum[1][tid] + wsum[2][tid] + wsum[3][tid];
        partial[blk * 4 + tid] = tot;   // unconditional write -> no memset needed
    }
}

__global__ void structure_loss_final(const float* __restrict__ partial,
                                     float* __restrict__ out)
{
    // 64 threads; 4 threads per batch, 16 float4 blocks each, coalesced.
    const int t = threadIdx.x;
    const float4* p4 = (const float4*)partial;   // one float4 per block
    float4 v = make_float4(0.f, 0.f, 0.f, 0.f);
    #pragma unroll
    for (int j = 0; j < 16; ++j) {
        const float4 q = p4[t * 16 + j];
        v.x += q.x; v.y += q.y; v.z += q.z; v.w += q.w;
    }
    #pragma unroll
    for (int off = 2; off > 0; off >>= 1) {
        v.x += __shfl_down(v.x, off);
        v.y += __shfl_down(v.y, off);
        v.z += __shfl_down(v.z, off);
        v.w += __shfl_down(v.w, off);
    }
    float loss = 0.0f;
    if ((t & 3) == 0) {
        const float sw = v.x, swb = v.y, inter = v.z, uni = v.w;
        loss = swb / sw + 1.0f - (inter + 1.0f) / (uni - inter + 1.0f);
    }
    #pragma unroll
    for (int off = 32; off >= 4; off >>= 1)
        loss += __shfl_down(loss, off);
    if (t == 0) out[0] = loss * (1.0f / (float)B_);
}

extern "C" void kernel_launch(void* const* d_in, const int* in_sizes, int n_in,
                              void* d_out, int out_size, void* d_ws, size_t ws_size,
                              hipStream_t stream) {
    const float* pred = (const float*)d_in[0];
    const float* mask = (const float*)d_in[1];
    float* out = (float*)d_out;
    float* partial = (float*)d_ws;      // 1024*4 floats, fully overwritten each call

    dim3 grid(W_ / TW, H_ / TH, B_);    // 8 x 8 x 16 = 1024 blocks
    structure_loss_tile<<<grid, 256, 0, stream>>>(pred, mask, partial);
    structure_loss_final<<<1, 64, 0, stream>>>(partial, out);
}